// Round 11
// baseline (914.740 us; speedup 1.0000x reference)
//
#include <hip/hip_runtime.h>

// Problem constants (from reference): z (64,128,64,64) f32, emb (256,128) f32
#define K_EMB   256
#define C_DIM   128
#define HW      4096            // 64*64
#define NPOS    262144          // 64*HW
#define Q_ELEMS 33554432        // 64*128*64*64
#define IDX_OFF Q_ELEMS         // idx chunk offset in d_out (floats)
#define LOSS_OFF (Q_ELEMS + NPOS)

#define BLKP 64                 // positions per block (z tile = 128c x 64p = 32 KB LDS)
#define NTHR 256                // 4 waves
#define NW   4
#define CC   8                  // c per emb chunk (8c x 256k = 8 KB)
#define NCHUNK (C_DIM / CC)     // 16
#define TM   8                  // positions per thread
#define TN   8                  // codes per thread

// ws layout (floats): [0,256) enorm, [256] loss accumulator, [512, 512+32768) embT (c*256+k)
#define WS_ENORM 0
#define WS_ACC   256
#define WS_EMBT  512
#define WS_NEED_FULL  ((WS_EMBT + C_DIM * K_EMB) * 4)

// Async global->LDS, 16 B per lane. Dest is wave-uniform base + lane*16 (m104):
// all our dest indices are t*16B + const, i.e. exactly base + lane*16 per wave.
#define GLOAD16(gsrc, ldst) __builtin_amdgcn_global_load_lds(                 \
    (const __attribute__((address_space(1))) void*)(gsrc),                    \
    (__attribute__((address_space(3))) void*)(ldst), 16, 0, 0)

// ---------------------------------------------------------------------------
// Kernel A: parallel emb transpose (one block per c) + enorm (block C_DIM).
// enorm: same ascending-c serial fmaf chain as the absmax-0 lineage (float4
// components consumed x,y,z,w = ascending c).
// ---------------------------------------------------------------------------
__global__ __launch_bounds__(K_EMB) void vq_prep(const float* __restrict__ emb,
                                                 float* __restrict__ ws,
                                                 int use_embT) {
    const int c = blockIdx.x, k = threadIdx.x;
    if (c < C_DIM) {
        if (use_embT) ws[WS_EMBT + c * K_EMB + k] = emb[k * C_DIM + c];
        if (c == 0 && k == 0) ws[WS_ACC] = 0.f;
    } else {
        const float4* __restrict__ er = reinterpret_cast<const float4*>(emb + k * C_DIM);
        float s = 0.f;
        #pragma unroll
        for (int j = 0; j < C_DIM / 4; ++j) {
            float4 v = er[j];
            s = fmaf(v.x, v.x, s);
            s = fmaf(v.y, v.y, s);
            s = fmaf(v.z, v.z, s);
            s = fmaf(v.w, v.w, s);
        }
        ws[WS_ENORM + k] = s;
    }
}

// ---------------------------------------------------------------------------
// Kernel 1: 8x8 register-tile VALU GEMM + argmin (LDS-delivery-economical).
//
// R15 (this round): R10 (4x8 tile) hit 288us / busy 64% with ZERO conflicts
// and no spill -- the model that closes: LDS DELIVERY bandwidth. ds_read_b128
// delivers 64 lanes x 16 B = 1 KB regardless of broadcast sharing; R10 moved
// 24 KB/c-step/block (4096 blk x 128 c x 24 KB = 12.9 GB -> 246us floor at
// 85 B/cyc/CU). Bytes per FMA = (TM+TN)*4/(TM*TN): 4x8 = 1.5, 8x8 = 1.0.
// So: 256 thr = 4 waves; wave w owns codes [64w,64w+64); lane = pg*8+cgl;
// thread = 8 pos x 8 codes; per c-step 4 ds_read_b128 (2z+2e, 2-way bank
// alias = free) + 72 fmaf. LDS traffic -33% -> ~164us floor. Argmin combine
// moved into registers (3-round shfl_xor butterfly over cgl bits,
// lexicographic (d,k) = exact first-min) so combine LDS shrinks to 2 KB:
// total 51 KB -> 3 blocks/CU = 12 waves/CU. gload_lds double-buffer (CC=8)
// kept from R10 (proven: no spill, vmcnt-counted, zero staging VGPRs).
//
// Numerics: bit-identical to the absmax-0 lineage. Every (pos,code) dot and
// every znorm is the same serial ascending-c fmaf chain over bit-copied
// data; d = (znorm - 2*acc) + enorm[k] exactly; thread scans its 8 codes
// ascending k strict <; butterfly takes lexicographic (d,k) min of disjoint
// code subsets = global (min d, first k); cross-wave combine ascending w
// strict < keeps lowest k on ties. Loss epilogue byte-for-byte R10: wave-0
// lanes own positions blk*64+0..63, same 128-term ascending-c chains, same
// shfl tree, same 4096 atomics.
// ---------------------------------------------------------------------------
template <int UT>
__global__ __launch_bounds__(NTHR, 3) void vq_main(const float* __restrict__ z,
                                                   const float* __restrict__ emb,
                                                   const float* __restrict__ ws,
                                                   float* __restrict__ out,
                                                   float* __restrict__ loss_acc) {
    __shared__ float zlds[C_DIM * BLKP];        // [c][p], 32 KB
    __shared__ float ebuf[2][CC * K_EMB];       // emb chunk double-buffer, 2 x 8 KB
    __shared__ float shen[K_EMB];               // enorm bit-copy, 1 KB
    __shared__ float shpb[NW * BLKP];           // per-wave bests, 1 KB
    __shared__ int   shpi[NW * BLKP];           // per-wave best idx, 1 KB

    const int t    = threadIdx.x;
    const int lane = t & 63;
    const int w    = t >> 6;                   // wave id: codes [64w, 64w+64)
    const int cgl  = lane & 7;                 // code sub-group within wave
    const int pg   = lane >> 3;                // position group
    const int p0   = pg * 8;                   // 8 positions per thread
    const int k0   = w * 64 + cgl * 8;         // 8 codes per thread
    const int blk  = blockIdx.x;
    const int b    = blk >> 6;                 // 64 blocks per image
    const int hw0  = (blk & 63) * BLKP;
    const size_t zoff = (size_t)b * (C_DIM * HW) + hw0;
    const float* __restrict__ zsrc = z + zoff;

    const float* __restrict__ embT    = ws + WS_EMBT;
    const float* __restrict__ enorm_g = ws + WS_ENORM;

    // ---- Prologue staging: z tile (32 KB, 8 passes) + emb chunk 0 ----
    // gload_lds dest = t*16B + const == wave-uniform base + lane*16 (valid).
    #pragma unroll
    for (int j = 0; j < (C_DIM * BLKP / 4) / NTHR; ++j) {   // 8 iters
        const int i4 = t + j * NTHR;           // float4 index into [c][p]
        const int c  = i4 >> 4;                // 16 float4 per c-row
        const int p4 = i4 & 15;
        GLOAD16(zsrc + (size_t)c * HW + p4 * 4, &zlds[i4 * 4]);
    }
    if (UT) {
        #pragma unroll
        for (int s = 0; s < 2; ++s) {          // 8 KB chunk = 512 float4
            const int i4 = t + s * NTHR;
            GLOAD16(embT + i4 * 4, &ebuf[0][i4 * 4]);
        }
    }
    shen[t] = enorm_g[t];                      // bit-copy (256 thr = 256 codes)
    __syncthreads();                           // drains vmcnt(0) + lgkmcnt(0)

    float acc[TM][TN];
    float zn[TM];
    #pragma unroll
    for (int i = 0; i < TM; ++i) {
        zn[i] = 0.f;
        #pragma unroll
        for (int j = 0; j < TN; ++j) acc[i][j] = 0.f;
    }

    if (UT) {
        for (int ch = 0; ch < NCHUNK; ++ch) {
            // Issue next chunk's loads first (zero VGPRs, counted on vmcnt).
            if (ch + 1 < NCHUNK) {
                const float* __restrict__ src = embT + (ch + 1) * CC * K_EMB;
                #pragma unroll
                for (int s = 0; s < 2; ++s) {
                    const int i4 = t + s * NTHR;
                    GLOAD16(src + i4 * 4, &ebuf[(ch + 1) & 1][i4 * 4]);
                }
            }
            const float* __restrict__ eb = ebuf[ch & 1];
            const int cbase = ch * CC;
            // Per c-step: 4 ds_read_b128 + 72 fmaf (1.0 B/FMA).
            //  z: addrs pg*32B (+16), pg/pg+4 alias 2-way = free
            //  e: addrs cgl*32B (+16) within wave quarter, 2-way = free
            #pragma unroll
            for (int c = 0; c < CC; ++c) {
                const float4 z0 = *reinterpret_cast<const float4*>(
                    &zlds[(cbase + c) * BLKP + p0]);
                const float4 z1 = *reinterpret_cast<const float4*>(
                    &zlds[(cbase + c) * BLKP + p0 + 4]);
                const float4 e0 = *reinterpret_cast<const float4*>(
                    &eb[c * K_EMB + k0]);
                const float4 e1 = *reinterpret_cast<const float4*>(
                    &eb[c * K_EMB + k0 + 4]);
                const float zz[TM] = {z0.x, z0.y, z0.z, z0.w,
                                      z1.x, z1.y, z1.z, z1.w};
                const float ee[TN] = {e0.x, e0.y, e0.z, e0.w,
                                      e1.x, e1.y, e1.z, e1.w};
                #pragma unroll
                for (int i = 0; i < TM; ++i) {
                    zn[i] = fmaf(zz[i], zz[i], zn[i]);   // serial asc-c chain
                    #pragma unroll
                    for (int j = 0; j < TN; ++j)
                        acc[i][j] = fmaf(zz[i], ee[j], acc[i][j]);
                }
            }
            if (ch + 1 < NCHUNK) {
                __syncthreads();   // drains vmcnt(0): chunk ch+1 visible,
                                   // ebuf[ch&1] released for next overwrite
            }
        }
    } else {
        // Fallback (no ws room for embT): direct global emb, correct but slow.
        #pragma unroll 2
        for (int c = 0; c < C_DIM; ++c) {
            const float4 z0 = *reinterpret_cast<const float4*>(&zlds[c * BLKP + p0]);
            const float4 z1 = *reinterpret_cast<const float4*>(&zlds[c * BLKP + p0 + 4]);
            const float zz[TM] = {z0.x, z0.y, z0.z, z0.w,
                                  z1.x, z1.y, z1.z, z1.w};
            float ee[TN];
            #pragma unroll
            for (int j = 0; j < TN; ++j) ee[j] = emb[(k0 + j) * C_DIM + c];
            #pragma unroll
            for (int i = 0; i < TM; ++i) {
                zn[i] = fmaf(zz[i], zz[i], zn[i]);
                #pragma unroll
                for (int j = 0; j < TN; ++j)
                    acc[i][j] = fmaf(zz[i], ee[j], acc[i][j]);
            }
        }
    }

    // ---- Thread-local argmin (8 codes, ascending k, strict <) ----
    float bb[TM];
    int   bi[TM];
    #pragma unroll
    for (int i = 0; i < TM; ++i) {
        float best = 3.402823466e38f;
        int   bidx = 0;
        #pragma unroll
        for (int j = 0; j < TN; ++j) {
            const float d = (zn[i] - 2.0f * acc[i][j]) + shen[k0 + j];
            if (d < best) { best = d; bidx = k0 + j; }   // strict < = first-min
        }
        bb[i] = best; bi[i] = bidx;
    }

    // ---- In-register wave combine: butterfly over cgl (lane bits 0..2).
    // Lexicographic (d,k) min of disjoint code subsets == global first-min.
    #pragma unroll
    for (int m = 1; m <= 4; m <<= 1) {
        #pragma unroll
        for (int i = 0; i < TM; ++i) {
            const float od = __shfl_xor(bb[i], m, 64);
            const int   ok = __shfl_xor(bi[i], m, 64);
            if (od < bb[i] || (od == bb[i] && ok < bi[i])) {
                bb[i] = od; bi[i] = ok;
            }
        }
    }
    if (cgl == 0) {   // one lane per position-group writes the wave's result
        #pragma unroll
        for (int i = 0; i < TM; ++i) {
            shpb[w * BLKP + p0 + i] = bb[i];
            shpi[w * BLKP + p0 + i] = bi[i];
        }
    }
    __syncthreads();

    if (t < BLKP) {   // wave 0: thread t owns position p = t
        const int p = t;
        float fb = shpb[p];
        int   fi = shpi[p];
        #pragma unroll
        for (int w2 = 1; w2 < NW; ++w2) {      // ascending w = ascending k range
            const float d = shpb[w2 * BLKP + p];
            if (d < fb) { fb = d; fi = shpi[w2 * BLKP + p]; }  // strict <
        }
        const int fin = fi;
        const int pos = blk * BLKP + p;
        __builtin_nontemporal_store((float)fin, &out[IDX_OFF + pos]);

        // Epilogue: q = z + (e - z), loss += (e - z)^2. z from LDS (bit-copy),
        // e from row-major emb via float4 (bit-equal to embT), ascending-c
        // 128-term chain identical to the absmax-0 lineage.
        float lsum = 0.f;
        float* qp = out + zoff + p;
        const float4* __restrict__ er =
            reinterpret_cast<const float4*>(emb + fin * C_DIM);
        #pragma unroll 4
        for (int j = 0; j < C_DIM / 4; ++j) {
            const float4 ev = er[j];
            const int c0 = j * 4;
            const float y0 = zlds[(c0 + 0) * BLKP + p];
            const float y1 = zlds[(c0 + 1) * BLKP + p];
            const float y2 = zlds[(c0 + 2) * BLKP + p];
            const float y3 = zlds[(c0 + 3) * BLKP + p];
            const float d0 = ev.x - y0, d1 = ev.y - y1;
            const float d2 = ev.z - y2, d3 = ev.w - y3;
            lsum = fmaf(d0, d0, lsum);
            lsum = fmaf(d1, d1, lsum);
            lsum = fmaf(d2, d2, lsum);
            lsum = fmaf(d3, d3, lsum);
            __builtin_nontemporal_store(y0 + d0, &qp[(size_t)(c0 + 0) * HW]);
            __builtin_nontemporal_store(y1 + d1, &qp[(size_t)(c0 + 1) * HW]);
            __builtin_nontemporal_store(y2 + d2, &qp[(size_t)(c0 + 2) * HW]);
            __builtin_nontemporal_store(y3 + d3, &qp[(size_t)(c0 + 3) * HW]);
        }

        // Wave-level reduction, one atomic per block (same 4096 partials).
        #pragma unroll
        for (int off = 32; off > 0; off >>= 1)
            lsum += __shfl_down(lsum, off, 64);
        if (p == 0) atomicAdd(loss_acc, lsum);
    }
}

// ---------------------------------------------------------------------------
// Kernel 2: finalize the two scalar losses.
// ---------------------------------------------------------------------------
__global__ void vq_finalize(const float* __restrict__ loss_acc,
                            float* __restrict__ out_losses) {
    float S = loss_acc[0];
    float mean = S / (float)Q_ELEMS;
    out_losses[0] = 0.25f * mean;  // commitment_loss
    out_losses[1] = mean;          // codebook_loss
}

extern "C" void kernel_launch(void* const* d_in, const int* in_sizes, int n_in,
                              void* d_out, int out_size, void* d_ws, size_t ws_size,
                              hipStream_t stream) {
    const float* z   = (const float*)d_in[0];
    const float* emb = (const float*)d_in[1];
    float* out = (float*)d_out;
    float* ws  = (float*)d_ws;

    int use_embT = (ws_size >= (size_t)WS_NEED_FULL) ? 1 : 0;

    vq_prep<<<C_DIM + 1, K_EMB, 0, stream>>>(emb, ws, use_embT);
    if (use_embT)
        vq_main<1><<<NPOS / BLKP, NTHR, 0, stream>>>(z, emb, ws, out, ws + WS_ACC);
    else
        vq_main<0><<<NPOS / BLKP, NTHR, 0, stream>>>(z, emb, ws, out, ws + WS_ACC);
    vq_finalize<<<1, 1, 0, stream>>>(ws + WS_ACC, out + LOSS_OFF);
}

// Round 12
// 543.270 us; speedup vs baseline: 1.6838x; 1.6838x over previous
//
#include <hip/hip_runtime.h>

// Problem constants (from reference): z (64,128,64,64) f32, emb (256,128) f32
#define K_EMB   256
#define C_DIM   128
#define HW      4096            // 64*64
#define NPOS    262144          // 64*HW
#define Q_ELEMS 33554432        // 64*128*64*64
#define IDX_OFF Q_ELEMS         // idx chunk offset in d_out (floats)
#define LOSS_OFF (Q_ELEMS + NPOS)

#define BLKP 64                 // positions per block (z tile = 128c x 64p = 32 KB LDS)
#define NTHR 256                // 4 waves
#define NW   4
#define CC   8                  // c per emb chunk (8c x 256k = 8 KB)
#define NCHUNK (C_DIM / CC)     // 16
#define TM   8                  // positions per thread
#define TN   8                  // codes per thread

// ws layout (floats): [0,256) enorm, [256] loss accumulator, [512, 512+32768) embT (c*256+k)
#define WS_ENORM 0
#define WS_ACC   256
#define WS_EMBT  512
#define WS_NEED_FULL  ((WS_EMBT + C_DIM * K_EMB) * 4)

// Async global->LDS, 16 B per lane. Dest is wave-uniform base + lane*16 (m104):
// all our dest indices are t*16B + const, i.e. exactly base + lane*16 per wave.
#define GLOAD16(gsrc, ldst) __builtin_amdgcn_global_load_lds(                 \
    (const __attribute__((address_space(1))) void*)(gsrc),                    \
    (__attribute__((address_space(3))) void*)(ldst), 16, 0, 0)

// ---------------------------------------------------------------------------
// Kernel A: parallel emb transpose (one block per c) + enorm (block C_DIM).
// enorm: same ascending-c serial fmaf chain as the absmax-0 lineage (float4
// components consumed x,y,z,w = ascending c).
// ---------------------------------------------------------------------------
__global__ __launch_bounds__(K_EMB) void vq_prep(const float* __restrict__ emb,
                                                 float* __restrict__ ws,
                                                 int use_embT) {
    const int c = blockIdx.x, k = threadIdx.x;
    if (c < C_DIM) {
        if (use_embT) ws[WS_EMBT + c * K_EMB + k] = emb[k * C_DIM + c];
        if (c == 0 && k == 0) ws[WS_ACC] = 0.f;
    } else {
        const float4* __restrict__ er = reinterpret_cast<const float4*>(emb + k * C_DIM);
        float s = 0.f;
        #pragma unroll
        for (int j = 0; j < C_DIM / 4; ++j) {
            float4 v = er[j];
            s = fmaf(v.x, v.x, s);
            s = fmaf(v.y, v.y, s);
            s = fmaf(v.z, v.z, s);
            s = fmaf(v.w, v.w, s);
        }
        ws[WS_ENORM + k] = s;
    }
}

// ---------------------------------------------------------------------------
// Kernel 1: 8x8 register-tile VALU GEMM + argmin (LDS-delivery-economical).
//
// R16 (this round): R15's ONLY failure was the register bound. With
// __launch_bounds__(256,3) the allocator cap is 512/3 ~= 170 regs; true
// demand (acc 64 + zn 8 + bb/bi 16 + operands 16 + addressing) is ~180-200,
// so the compiler SPILLED the accumulators to scratch: FETCH 67MB->1.16GB,
// WRITE 132MB->1.20GB, busy 27%. Precedent: R9 held ~130+ live floats with
// __launch_bounds__(256,2) and did NOT spill. Fix is one variable: bound
// (256,2). If the real allocation lands <=170 the HW still runs 3
// waves/SIMD (LDS 51KB allows 3 blocks/CU); if not, 2 waves/SIMD suffice
// here because the loop has NO SMEM drain (R9's killer): per c-step is 4
// counted ds_read_b128 + 144 cyc fmaf -> duty ceiling ~75%.
//
// Model being tested (from R10's closed arithmetic): ds_read_b128 delivers
// 64 lanes x 16 B = 1 KB regardless of broadcast; bytes/FMA =
// (TM+TN)*4/(TM*TN): 4x8 = 1.5 (R10, 246us floor, measured 288), 8x8 =
// 1.0 -> 165us floor. Per c-step: 4 ds_read_b128 (2z+2e, 2-way bank alias
// = free) + 72 fmaf. gload_lds double-buffer (CC=8) from R10: zero staging
// VGPRs, counted on vmcnt, sealed by __syncthreads' vmcnt(0) drain.
//
// Numerics: bit-identical to the absmax-0 lineage. Every (pos,code) dot and
// every znorm is the same serial ascending-c fmaf chain over bit-copied
// data; d = (znorm - 2*acc) + enorm[k] exactly; thread scans its 8 codes
// ascending k strict <; shfl_xor butterfly takes lexicographic (d,k) min
// of disjoint code subsets = global (min d, first k); cross-wave combine
// ascending w strict < keeps lowest k on ties. Loss epilogue byte-for-byte
// R10: wave-0 lanes own positions blk*64+0..63, same 128-term ascending-c
// chains, same shfl tree, same 4096 atomics.
// ---------------------------------------------------------------------------
template <int UT>
__global__ __launch_bounds__(NTHR, 2) void vq_main(const float* __restrict__ z,
                                                   const float* __restrict__ emb,
                                                   const float* __restrict__ ws,
                                                   float* __restrict__ out,
                                                   float* __restrict__ loss_acc) {
    __shared__ float zlds[C_DIM * BLKP];        // [c][p], 32 KB
    __shared__ float ebuf[2][CC * K_EMB];       // emb chunk double-buffer, 2 x 8 KB
    __shared__ float shen[K_EMB];               // enorm bit-copy, 1 KB
    __shared__ float shpb[NW * BLKP];           // per-wave bests, 1 KB
    __shared__ int   shpi[NW * BLKP];           // per-wave best idx, 1 KB

    const int t    = threadIdx.x;
    const int lane = t & 63;
    const int w    = t >> 6;                   // wave id: codes [64w, 64w+64)
    const int cgl  = lane & 7;                 // code sub-group within wave
    const int pg   = lane >> 3;                // position group
    const int p0   = pg * 8;                   // 8 positions per thread
    const int k0   = w * 64 + cgl * 8;         // 8 codes per thread
    const int blk  = blockIdx.x;
    const int b    = blk >> 6;                 // 64 blocks per image
    const int hw0  = (blk & 63) * BLKP;
    const size_t zoff = (size_t)b * (C_DIM * HW) + hw0;
    const float* __restrict__ zsrc = z + zoff;

    const float* __restrict__ embT    = ws + WS_EMBT;
    const float* __restrict__ enorm_g = ws + WS_ENORM;

    // ---- Prologue staging: z tile (32 KB, 8 passes) + emb chunk 0 ----
    // gload_lds dest = t*16B + const == wave-uniform base + lane*16 (valid).
    #pragma unroll
    for (int j = 0; j < (C_DIM * BLKP / 4) / NTHR; ++j) {   // 8 iters
        const int i4 = t + j * NTHR;           // float4 index into [c][p]
        const int c  = i4 >> 4;                // 16 float4 per c-row
        const int p4 = i4 & 15;
        GLOAD16(zsrc + (size_t)c * HW + p4 * 4, &zlds[i4 * 4]);
    }
    if (UT) {
        #pragma unroll
        for (int s = 0; s < 2; ++s) {          // 8 KB chunk = 512 float4
            const int i4 = t + s * NTHR;
            GLOAD16(embT + i4 * 4, &ebuf[0][i4 * 4]);
        }
    }
    shen[t] = enorm_g[t];                      // bit-copy (256 thr = 256 codes)
    __syncthreads();                           // drains vmcnt(0) + lgkmcnt(0)

    float acc[TM][TN];
    float zn[TM];
    #pragma unroll
    for (int i = 0; i < TM; ++i) {
        zn[i] = 0.f;
        #pragma unroll
        for (int j = 0; j < TN; ++j) acc[i][j] = 0.f;
    }

    if (UT) {
        for (int ch = 0; ch < NCHUNK; ++ch) {
            // Issue next chunk's loads first (zero VGPRs, counted on vmcnt).
            if (ch + 1 < NCHUNK) {
                const float* __restrict__ src = embT + (ch + 1) * CC * K_EMB;
                #pragma unroll
                for (int s = 0; s < 2; ++s) {
                    const int i4 = t + s * NTHR;
                    GLOAD16(src + i4 * 4, &ebuf[(ch + 1) & 1][i4 * 4]);
                }
            }
            const float* __restrict__ eb = ebuf[ch & 1];
            const int cbase = ch * CC;
            // Per c-step: 4 ds_read_b128 + 72 fmaf (1.0 B/FMA).
            //  z: addrs pg*32B (+16), pg/pg+4 alias 2-way = free
            //  e: addrs cgl*32B (+16) within wave quarter, 2-way = free
            #pragma unroll
            for (int c = 0; c < CC; ++c) {
                const float4 z0 = *reinterpret_cast<const float4*>(
                    &zlds[(cbase + c) * BLKP + p0]);
                const float4 z1 = *reinterpret_cast<const float4*>(
                    &zlds[(cbase + c) * BLKP + p0 + 4]);
                const float4 e0 = *reinterpret_cast<const float4*>(
                    &eb[c * K_EMB + k0]);
                const float4 e1 = *reinterpret_cast<const float4*>(
                    &eb[c * K_EMB + k0 + 4]);
                const float zz[TM] = {z0.x, z0.y, z0.z, z0.w,
                                      z1.x, z1.y, z1.z, z1.w};
                const float ee[TN] = {e0.x, e0.y, e0.z, e0.w,
                                      e1.x, e1.y, e1.z, e1.w};
                #pragma unroll
                for (int i = 0; i < TM; ++i) {
                    zn[i] = fmaf(zz[i], zz[i], zn[i]);   // serial asc-c chain
                    #pragma unroll
                    for (int j = 0; j < TN; ++j)
                        acc[i][j] = fmaf(zz[i], ee[j], acc[i][j]);
                }
            }
            if (ch + 1 < NCHUNK) {
                __syncthreads();   // drains vmcnt(0): chunk ch+1 visible,
                                   // ebuf[ch&1] released for next overwrite
            }
        }
    } else {
        // Fallback (no ws room for embT): direct global emb, correct but slow.
        #pragma unroll 2
        for (int c = 0; c < C_DIM; ++c) {
            const float4 z0 = *reinterpret_cast<const float4*>(&zlds[c * BLKP + p0]);
            const float4 z1 = *reinterpret_cast<const float4*>(&zlds[c * BLKP + p0 + 4]);
            const float zz[TM] = {z0.x, z0.y, z0.z, z0.w,
                                  z1.x, z1.y, z1.z, z1.w};
            float ee[TN];
            #pragma unroll
            for (int j = 0; j < TN; ++j) ee[j] = emb[(k0 + j) * C_DIM + c];
            #pragma unroll
            for (int i = 0; i < TM; ++i) {
                zn[i] = fmaf(zz[i], zz[i], zn[i]);
                #pragma unroll
                for (int j = 0; j < TN; ++j)
                    acc[i][j] = fmaf(zz[i], ee[j], acc[i][j]);
            }
        }
    }

    // ---- Thread-local argmin (8 codes, ascending k, strict <) ----
    float bb[TM];
    int   bi[TM];
    #pragma unroll
    for (int i = 0; i < TM; ++i) {
        float best = 3.402823466e38f;
        int   bidx = 0;
        #pragma unroll
        for (int j = 0; j < TN; ++j) {
            const float d = (zn[i] - 2.0f * acc[i][j]) + shen[k0 + j];
            if (d < best) { best = d; bidx = k0 + j; }   // strict < = first-min
        }
        bb[i] = best; bi[i] = bidx;
    }

    // ---- In-register wave combine: butterfly over cgl (lane bits 0..2).
    // Lexicographic (d,k) min of disjoint code subsets == global first-min.
    #pragma unroll
    for (int m = 1; m <= 4; m <<= 1) {
        #pragma unroll
        for (int i = 0; i < TM; ++i) {
            const float od = __shfl_xor(bb[i], m, 64);
            const int   ok = __shfl_xor(bi[i], m, 64);
            if (od < bb[i] || (od == bb[i] && ok < bi[i])) {
                bb[i] = od; bi[i] = ok;
            }
        }
    }
    if (cgl == 0) {   // one lane per position-group writes the wave's result
        #pragma unroll
        for (int i = 0; i < TM; ++i) {
            shpb[w * BLKP + p0 + i] = bb[i];
            shpi[w * BLKP + p0 + i] = bi[i];
        }
    }
    __syncthreads();

    if (t < BLKP) {   // wave 0: thread t owns position p = t
        const int p = t;
        float fb = shpb[p];
        int   fi = shpi[p];
        #pragma unroll
        for (int w2 = 1; w2 < NW; ++w2) {      // ascending w = ascending k range
            const float d = shpb[w2 * BLKP + p];
            if (d < fb) { fb = d; fi = shpi[w2 * BLKP + p]; }  // strict <
        }
        const int fin = fi;
        const int pos = blk * BLKP + p;
        __builtin_nontemporal_store((float)fin, &out[IDX_OFF + pos]);

        // Epilogue: q = z + (e - z), loss += (e - z)^2. z from LDS (bit-copy),
        // e from row-major emb via float4 (bit-equal to embT), ascending-c
        // 128-term chain identical to the absmax-0 lineage.
        float lsum = 0.f;
        float* qp = out + zoff + p;
        const float4* __restrict__ er =
            reinterpret_cast<const float4*>(emb + fin * C_DIM);
        #pragma unroll 4
        for (int j = 0; j < C_DIM / 4; ++j) {
            const float4 ev = er[j];
            const int c0 = j * 4;
            const float y0 = zlds[(c0 + 0) * BLKP + p];
            const float y1 = zlds[(c0 + 1) * BLKP + p];
            const float y2 = zlds[(c0 + 2) * BLKP + p];
            const float y3 = zlds[(c0 + 3) * BLKP + p];
            const float d0 = ev.x - y0, d1 = ev.y - y1;
            const float d2 = ev.z - y2, d3 = ev.w - y3;
            lsum = fmaf(d0, d0, lsum);
            lsum = fmaf(d1, d1, lsum);
            lsum = fmaf(d2, d2, lsum);
            lsum = fmaf(d3, d3, lsum);
            __builtin_nontemporal_store(y0 + d0, &qp[(size_t)(c0 + 0) * HW]);
            __builtin_nontemporal_store(y1 + d1, &qp[(size_t)(c0 + 1) * HW]);
            __builtin_nontemporal_store(y2 + d2, &qp[(size_t)(c0 + 2) * HW]);
            __builtin_nontemporal_store(y3 + d3, &qp[(size_t)(c0 + 3) * HW]);
        }

        // Wave-level reduction, one atomic per block (same 4096 partials).
        #pragma unroll
        for (int off = 32; off > 0; off >>= 1)
            lsum += __shfl_down(lsum, off, 64);
        if (p == 0) atomicAdd(loss_acc, lsum);
    }
}

// ---------------------------------------------------------------------------
// Kernel 2: finalize the two scalar losses.
// ---------------------------------------------------------------------------
__global__ void vq_finalize(const float* __restrict__ loss_acc,
                            float* __restrict__ out_losses) {
    float S = loss_acc[0];
    float mean = S / (float)Q_ELEMS;
    out_losses[0] = 0.25f * mean;  // commitment_loss
    out_losses[1] = mean;          // codebook_loss
}

extern "C" void kernel_launch(void* const* d_in, const int* in_sizes, int n_in,
                              void* d_out, int out_size, void* d_ws, size_t ws_size,
                              hipStream_t stream) {
    const float* z   = (const float*)d_in[0];
    const float* emb = (const float*)d_in[1];
    float* out = (float*)d_out;
    float* ws  = (float*)d_ws;

    int use_embT = (ws_size >= (size_t)WS_NEED_FULL) ? 1 : 0;

    vq_prep<<<C_DIM + 1, K_EMB, 0, stream>>>(emb, ws, use_embT);
    if (use_embT)
        vq_main<1><<<NPOS / BLKP, NTHR, 0, stream>>>(z, emb, ws, out, ws + WS_ACC);
    else
        vq_main<0><<<NPOS / BLKP, NTHR, 0, stream>>>(z, emb, ws, out, ws + WS_ACC);
    vq_finalize<<<1, 1, 0, stream>>>(ws + WS_ACC, out + LOSS_OFF);
}

// Round 13
// 419.622 us; speedup vs baseline: 2.1799x; 1.2947x over previous
//
#include <hip/hip_runtime.h>

// Problem constants (from reference): z (64,128,64,64) f32, emb (256,128) f32
#define K_EMB   256
#define C_DIM   128
#define HW      4096            // 64*64
#define NPOS    262144          // 64*HW
#define Q_ELEMS 33554432        // 64*128*64*64
#define IDX_OFF Q_ELEMS         // idx chunk offset in d_out (floats)
#define LOSS_OFF (Q_ELEMS + NPOS)

#define BLKP 64                 // positions per block (z tile = 128c x 64p = 32 KB LDS)
#define NTHR 256                // 4 waves
#define NW   4
#define CC   8                  // c per emb chunk (8c x 256k = 8 KB)
#define NCHUNK (C_DIM / CC)     // 16
#define TM   8                  // positions per thread
#define TN   8                  // codes per thread

// ws layout (floats): [0,256) enorm, [256] loss accumulator, [512, 512+32768) embT (c*256+k)
#define WS_ENORM 0
#define WS_ACC   256
#define WS_EMBT  512
#define WS_NEED_FULL  ((WS_EMBT + C_DIM * K_EMB) * 4)

// Async global->LDS, 16 B per lane. Dest is wave-uniform base + lane*16 (m104):
// all our dest indices are t*16B + const, i.e. exactly base + lane*16 per wave.
#define GLOAD16(gsrc, ldst) __builtin_amdgcn_global_load_lds(                 \
    (const __attribute__((address_space(1))) void*)(gsrc),                    \
    (__attribute__((address_space(3))) void*)(ldst), 16, 0, 0)

// ---------------------------------------------------------------------------
// Kernel A: parallel emb transpose (one block per c) + enorm (block C_DIM).
// enorm: same ascending-c serial fmaf chain as the absmax-0 lineage (float4
// components consumed x,y,z,w = ascending c).
// ---------------------------------------------------------------------------
__global__ __launch_bounds__(K_EMB) void vq_prep(const float* __restrict__ emb,
                                                 float* __restrict__ ws,
                                                 int use_embT) {
    const int c = blockIdx.x, k = threadIdx.x;
    if (c < C_DIM) {
        if (use_embT) ws[WS_EMBT + c * K_EMB + k] = emb[k * C_DIM + c];
        if (c == 0 && k == 0) ws[WS_ACC] = 0.f;
    } else {
        const float4* __restrict__ er = reinterpret_cast<const float4*>(emb + k * C_DIM);
        float s = 0.f;
        #pragma unroll
        for (int j = 0; j < C_DIM / 4; ++j) {
            float4 v = er[j];
            s = fmaf(v.x, v.x, s);
            s = fmaf(v.y, v.y, s);
            s = fmaf(v.z, v.z, s);
            s = fmaf(v.w, v.w, s);
        }
        ws[WS_ENORM + k] = s;
    }
}

// ---------------------------------------------------------------------------
// Kernel 1: 8x8 register-tile VALU GEMM + argmin.
//
// R17 (this round): R16 halved the spill (VGPR 84->128) but the allocator
// parked on the 128-reg occupancy cliff and spilled the remainder (WRITE
// 317 MB = ~185 MB scratch). True in-loop pressure was ~135: acc 64 + zn 8
// + FULL-unroll operand hoisting (~24-32) + addressing. Fix = get demand
// under 128 instead of fighting the heuristic:
//   (1) zn[8] and its 8 fma/c-step REMOVED from the loop; znorm computed by
//       a wave-0 LDS prepass into shz[64] (R7-proven overlap; same serial
//       ascending-c fmaf chain over the same staged zlds = same bits).
//   (2) #pragma unroll 4 on the c-loop caps the scheduler's load-hoisting
//       window (R12's spill margin was exactly this hoisted-operand set).
// New peak ~95-110 < 128 -> no spill, and <=128 VGPR allows 16 waves/CU so
// all 3 LDS-permitted blocks/CU (51.5 KB) become resident.
//
// Design point (model from R10's closed arithmetic): ds_read_b128 delivers
// 64 lanes x 16 B regardless of broadcast; bytes/FMA = (TM+TN)*4/(TM*TN) =
// 1.0 at 8x8 (vs 1.5 at R10's 4x8). LDS pipe: 4 b128 x 12 cyc per wave per
// c-step -> 164 us total (binding); VALU 109 us -> predicted busy ~67%.
// Per c-step: 4 ds_read_b128 (2z+2e, 2-way bank alias = free) + 64 fmaf.
// gload_lds double-buffer (CC=8): zero staging VGPRs, counted on vmcnt,
// sealed by __syncthreads' vmcnt(0)+lgkmcnt(0) drain.
//
// Numerics: bit-identical to the absmax-0 lineage. Every (pos,code) dot is
// the same serial ascending-c fmaf chain over bit-copied data; znorm is the
// same serial ascending-c chain (prepass, same staged bits); d = (znorm -
// 2*acc) + enorm[k] exactly; thread scans its 8 codes ascending k strict <;
// shfl_xor butterfly takes lexicographic (d,k) min of disjoint code subsets
// = global (min d, first k); cross-wave combine ascending w strict < keeps
// lowest k on ties. Loss epilogue byte-for-byte R10: wave-0 lanes own
// positions blk*64+0..63, same 128-term ascending-c chains, same shfl tree,
// same 4096 atomics.
// ---------------------------------------------------------------------------
template <int UT>
__global__ __launch_bounds__(NTHR, 2) void vq_main(const float* __restrict__ z,
                                                   const float* __restrict__ emb,
                                                   const float* __restrict__ ws,
                                                   float* __restrict__ out,
                                                   float* __restrict__ loss_acc) {
    __shared__ float zlds[C_DIM * BLKP];        // [c][p], 32 KB
    __shared__ float ebuf[2][CC * K_EMB];       // emb chunk double-buffer, 2 x 8 KB
    __shared__ float shen[K_EMB];               // enorm bit-copy, 1 KB
    __shared__ float shz[BLKP];                 // znorm per position, 256 B
    __shared__ float shpb[NW * BLKP];           // per-wave bests, 1 KB
    __shared__ int   shpi[NW * BLKP];           // per-wave best idx, 1 KB

    const int t    = threadIdx.x;
    const int lane = t & 63;
    const int w    = t >> 6;                   // wave id: codes [64w, 64w+64)
    const int cgl  = lane & 7;                 // code sub-group within wave
    const int pg   = lane >> 3;                // position group
    const int p0   = pg * 8;                   // 8 positions per thread
    const int k0   = w * 64 + cgl * 8;         // 8 codes per thread
    const int blk  = blockIdx.x;
    const int b    = blk >> 6;                 // 64 blocks per image
    const int hw0  = (blk & 63) * BLKP;
    const size_t zoff = (size_t)b * (C_DIM * HW) + hw0;
    const float* __restrict__ zsrc = z + zoff;

    const float* __restrict__ embT    = ws + WS_EMBT;
    const float* __restrict__ enorm_g = ws + WS_ENORM;

    // ---- Prologue staging: z tile (32 KB, 8 passes) + emb chunk 0 ----
    // gload_lds dest = t*16B + const == wave-uniform base + lane*16 (valid).
    #pragma unroll
    for (int j = 0; j < (C_DIM * BLKP / 4) / NTHR; ++j) {   // 8 iters
        const int i4 = t + j * NTHR;           // float4 index into [c][p]
        const int c  = i4 >> 4;                // 16 float4 per c-row
        const int p4 = i4 & 15;
        GLOAD16(zsrc + (size_t)c * HW + p4 * 4, &zlds[i4 * 4]);
    }
    if (UT) {
        #pragma unroll
        for (int s = 0; s < 2; ++s) {          // 8 KB chunk = 512 float4
            const int i4 = t + s * NTHR;
            GLOAD16(embT + i4 * 4, &ebuf[0][i4 * 4]);
        }
    }
    shen[t] = enorm_g[t];                      // bit-copy (256 thr = 256 codes)
    __syncthreads();                           // drains vmcnt(0) + lgkmcnt(0)

    // ---- Wave 0: znorm prepass (one serial ascending-c chain per pos). ----
    // Same bits as the in-loop version: same staged zlds data, same chain
    // order. Consumed only after the post-loop barrier-protected region.
    if (t < BLKP) {
        float zn = 0.f;
        #pragma unroll 8
        for (int c = 0; c < C_DIM; ++c)
            zn = fmaf(zlds[c * BLKP + t], zlds[c * BLKP + t], zn);
        shz[t] = zn;
    }

    float acc[TM][TN];
    #pragma unroll
    for (int i = 0; i < TM; ++i)
        #pragma unroll
        for (int j = 0; j < TN; ++j) acc[i][j] = 0.f;

    if (UT) {
        for (int ch = 0; ch < NCHUNK; ++ch) {
            // Issue next chunk's loads first (zero VGPRs, counted on vmcnt).
            if (ch + 1 < NCHUNK) {
                const float* __restrict__ src = embT + (ch + 1) * CC * K_EMB;
                #pragma unroll
                for (int s = 0; s < 2; ++s) {
                    const int i4 = t + s * NTHR;
                    GLOAD16(src + i4 * 4, &ebuf[(ch + 1) & 1][i4 * 4]);
                }
            }
            const float* __restrict__ eb = ebuf[ch & 1];
            const int cbase = ch * CC;
            // Per c-step: 4 ds_read_b128 + 64 fmaf (1.0 B/FMA).
            // unroll 4 (not full): caps operand-hoisting register pressure.
            #pragma unroll 4
            for (int c = 0; c < CC; ++c) {
                const float4 z0 = *reinterpret_cast<const float4*>(
                    &zlds[(cbase + c) * BLKP + p0]);
                const float4 z1 = *reinterpret_cast<const float4*>(
                    &zlds[(cbase + c) * BLKP + p0 + 4]);
                const float4 e0 = *reinterpret_cast<const float4*>(
                    &eb[c * K_EMB + k0]);
                const float4 e1 = *reinterpret_cast<const float4*>(
                    &eb[c * K_EMB + k0 + 4]);
                const float zz[TM] = {z0.x, z0.y, z0.z, z0.w,
                                      z1.x, z1.y, z1.z, z1.w};
                const float ee[TN] = {e0.x, e0.y, e0.z, e0.w,
                                      e1.x, e1.y, e1.z, e1.w};
                #pragma unroll
                for (int i = 0; i < TM; ++i)
                    #pragma unroll
                    for (int j = 0; j < TN; ++j)
                        acc[i][j] = fmaf(zz[i], ee[j], acc[i][j]);
            }
            if (ch + 1 < NCHUNK) {
                __syncthreads();   // drains vmcnt(0): chunk ch+1 visible,
                                   // ebuf[ch&1] released for next overwrite
            }
        }
    } else {
        // Fallback (no ws room for embT): direct global emb, correct but slow.
        #pragma unroll 2
        for (int c = 0; c < C_DIM; ++c) {
            const float4 z0 = *reinterpret_cast<const float4*>(&zlds[c * BLKP + p0]);
            const float4 z1 = *reinterpret_cast<const float4*>(&zlds[c * BLKP + p0 + 4]);
            const float zz[TM] = {z0.x, z0.y, z0.z, z0.w,
                                  z1.x, z1.y, z1.z, z1.w};
            float ee[TN];
            #pragma unroll
            for (int j = 0; j < TN; ++j) ee[j] = emb[(k0 + j) * C_DIM + c];
            #pragma unroll
            for (int i = 0; i < TM; ++i)
                #pragma unroll
                for (int j = 0; j < TN; ++j)
                    acc[i][j] = fmaf(zz[i], ee[j], acc[i][j]);
        }
    }
    __syncthreads();   // shz stable for all waves (also seals last chunk)

    // ---- Thread-local argmin (8 codes, ascending k, strict <) ----
    float bb[TM];
    int   bi[TM];
    #pragma unroll
    for (int i = 0; i < TM; ++i) {
        const float zn = shz[p0 + i];
        float best = 3.402823466e38f;
        int   bidx = 0;
        #pragma unroll
        for (int j = 0; j < TN; ++j) {
            const float d = (zn - 2.0f * acc[i][j]) + shen[k0 + j];
            if (d < best) { best = d; bidx = k0 + j; }   // strict < = first-min
        }
        bb[i] = best; bi[i] = bidx;
    }

    // ---- In-register wave combine: butterfly over cgl (lane bits 0..2).
    // Lexicographic (d,k) min of disjoint code subsets == global first-min.
    #pragma unroll
    for (int m = 1; m <= 4; m <<= 1) {
        #pragma unroll
        for (int i = 0; i < TM; ++i) {
            const float od = __shfl_xor(bb[i], m, 64);
            const int   ok = __shfl_xor(bi[i], m, 64);
            if (od < bb[i] || (od == bb[i] && ok < bi[i])) {
                bb[i] = od; bi[i] = ok;
            }
        }
    }
    if (cgl == 0) {   // one lane per position-group writes the wave's result
        #pragma unroll
        for (int i = 0; i < TM; ++i) {
            shpb[w * BLKP + p0 + i] = bb[i];
            shpi[w * BLKP + p0 + i] = bi[i];
        }
    }
    __syncthreads();

    if (t < BLKP) {   // wave 0: thread t owns position p = t
        const int p = t;
        float fb = shpb[p];
        int   fi = shpi[p];
        #pragma unroll
        for (int w2 = 1; w2 < NW; ++w2) {      // ascending w = ascending k range
            const float d = shpb[w2 * BLKP + p];
            if (d < fb) { fb = d; fi = shpi[w2 * BLKP + p]; }  // strict <
        }
        const int fin = fi;
        const int pos = blk * BLKP + p;
        __builtin_nontemporal_store((float)fin, &out[IDX_OFF + pos]);

        // Epilogue: q = z + (e - z), loss += (e - z)^2. z from LDS (bit-copy),
        // e from row-major emb via float4 (bit-equal to embT), ascending-c
        // 128-term chain identical to the absmax-0 lineage.
        float lsum = 0.f;
        float* qp = out + zoff + p;
        const float4* __restrict__ er =
            reinterpret_cast<const float4*>(emb + fin * C_DIM);
        #pragma unroll 4
        for (int j = 0; j < C_DIM / 4; ++j) {
            const float4 ev = er[j];
            const int c0 = j * 4;
            const float y0 = zlds[(c0 + 0) * BLKP + p];
            const float y1 = zlds[(c0 + 1) * BLKP + p];
            const float y2 = zlds[(c0 + 2) * BLKP + p];
            const float y3 = zlds[(c0 + 3) * BLKP + p];
            const float d0 = ev.x - y0, d1 = ev.y - y1;
            const float d2 = ev.z - y2, d3 = ev.w - y3;
            lsum = fmaf(d0, d0, lsum);
            lsum = fmaf(d1, d1, lsum);
            lsum = fmaf(d2, d2, lsum);
            lsum = fmaf(d3, d3, lsum);
            __builtin_nontemporal_store(y0 + d0, &qp[(size_t)(c0 + 0) * HW]);
            __builtin_nontemporal_store(y1 + d1, &qp[(size_t)(c0 + 1) * HW]);
            __builtin_nontemporal_store(y2 + d2, &qp[(size_t)(c0 + 2) * HW]);
            __builtin_nontemporal_store(y3 + d3, &qp[(size_t)(c0 + 3) * HW]);
        }

        // Wave-level reduction, one atomic per block (same 4096 partials).
        #pragma unroll
        for (int off = 32; off > 0; off >>= 1)
            lsum += __shfl_down(lsum, off, 64);
        if (p == 0) atomicAdd(loss_acc, lsum);
    }
}

// ---------------------------------------------------------------------------
// Kernel 2: finalize the two scalar losses.
// ---------------------------------------------------------------------------
__global__ void vq_finalize(const float* __restrict__ loss_acc,
                            float* __restrict__ out_losses) {
    float S = loss_acc[0];
    float mean = S / (float)Q_ELEMS;
    out_losses[0] = 0.25f * mean;  // commitment_loss
    out_losses[1] = mean;          // codebook_loss
}

extern "C" void kernel_launch(void* const* d_in, const int* in_sizes, int n_in,
                              void* d_out, int out_size, void* d_ws, size_t ws_size,
                              hipStream_t stream) {
    const float* z   = (const float*)d_in[0];
    const float* emb = (const float*)d_in[1];
    float* out = (float*)d_out;
    float* ws  = (float*)d_ws;

    int use_embT = (ws_size >= (size_t)WS_NEED_FULL) ? 1 : 0;

    vq_prep<<<C_DIM + 1, K_EMB, 0, stream>>>(emb, ws, use_embT);
    if (use_embT)
        vq_main<1><<<NPOS / BLKP, NTHR, 0, stream>>>(z, emb, ws, out, ws + WS_ACC);
    else
        vq_main<0><<<NPOS / BLKP, NTHR, 0, stream>>>(z, emb, ws, out, ws + WS_ACC);
    vq_finalize<<<1, 1, 0, stream>>>(ws + WS_ACC, out + LOSS_OFF);
}